// Round 9
// baseline (1223.091 us; speedup 1.0000x reference)
//
#include <hip/hip_runtime.h>

#define T_STEPS 1024
#define NZV 60          // valid z width
#define H 128
#define NY 8
#define NU 4
#define ZSTR 72         // padded LDS stride (shorts) for z
#define HSTR 136        // padded LDS stride (shorts) for h1

typedef __attribute__((ext_vector_type(8))) short bf16x8;
typedef __attribute__((ext_vector_type(4))) short bf16x4;
typedef __attribute__((ext_vector_type(4))) float f32x4;
typedef __attribute__((ext_vector_type(2))) unsigned uint2v;

union U4 { unsigned u[4]; bf16x8 v; };
union U2 { unsigned u[2]; bf16x4 v; };

__device__ __forceinline__ unsigned short f2bf(float x) {
    unsigned u = __float_as_uint(x);
    u += 0x7FFFu + ((u >> 16) & 1u);
    return (unsigned short)(u >> 16);
}

__device__ __forceinline__ unsigned cvt_pk_bf16(float lo, float hi) {
    unsigned r;
    asm("v_cvt_pk_bf16_f32 %0, %1, %2" : "=v"(r) : "v"(lo), "v"(hi));
    return r;
}

__device__ __forceinline__ unsigned swz16(unsigned v) {
    return (unsigned)__builtin_amdgcn_ds_swizzle((int)v, 0x401F);  // xor lane^16
}

// tanh(x) = 1 - 2/(exp(2x)+1); exp2 saturates so no clamp needed.
__device__ __forceinline__ float tanh_fast(float x) {
    float e = __builtin_amdgcn_exp2f(x * 2.8853900817779268f);
    return fmaf(-2.0f, __builtin_amdgcn_rcpf(e + 1.0f), 1.0f);
}

#define MFMA32 __builtin_amdgcn_mfma_f32_16x16x32_bf16

// one 16x16x16 bf16 MFMA (GEMM3 partial, K=16 = this wave's h2 cols).
// asm: s_nop 1 guards VALU->MFMA src; s_nop 7 x2 guards MFMA D -> ds_write.
__device__ __forceinline__ f32x4 gemm3_one(bf16x4 a, bf16x4 b, f32x4 c) {
    asm("s_nop 1\n\t"
        "v_mfma_f32_16x16x16_bf16 %0, %1, %2, %0\n\t"
        "s_nop 7\n\t"
        "s_nop 7"
        : "+v"(c) : "v"(a), "v"(b));
    return c;
}

__global__ __launch_bounds__(512, 4)
void cstr_scan_kernel(const float* __restrict__ u_g, const float* __restrict__ z0_g,
                      const float* __restrict__ W1, const float* __restrict__ b1,
                      const float* __restrict__ W2, const float* __restrict__ b2,
                      const float* __restrict__ W3, const float* __restrict__ b3,
                      float* __restrict__ out) {
    __shared__ unsigned short zbuf[2][16][ZSTR];
    __shared__ unsigned short h1s[16][HSTR];
    __shared__ f32x4 ypart[8][32];           // per-wave GEMM3 partials (kg<2 lanes only)
    __shared__ float ybuf[32][16][NY];       // 32-deep y ring, flushed 16/step
    __shared__ float ubuf[2][16][16][NU];    // u windows (DMA'd)

    const int tid   = threadIdx.x;
    const int wid   = tid >> 6;          // 0..7
    const int lane  = tid & 63;
    const int b0    = blockIdx.x * 16;   // batch row base
    const int col   = lane & 15;         // batch row (swapped C-frags)
    const int kg    = lane >> 4;         // 0..3
    const int urow  = lane >> 2;         // shift row
    const int uc    = lane & 3;
    const int nbase = wid * 16;          // this wave's hidden-col base (1 n-tile)
    const int frow  = tid >> 4;          // flush: batch row (tid<256)
    const int ftoff = tid & 15;          // flush: time offset

    // ---- preload weight fragments (A-operands of swapped MFMAs) ----
    bf16x8 w1f[2], w2f[4];
    bf16x4 w3a;
    f32x4 b1t, b2t, b3t;
#pragma unroll
    for (int r = 0; r < 4; ++r) {
        b1t[r] = b1[nbase + kg * 4 + r];
        b2t[r] = b2[nbase + kg * 4 + r];
        b3t[r] = (wid == 0 && kg * 4 + r < NY) ? b3[kg * 4 + r] : 0.f;
    }
#pragma unroll
    for (int kc = 0; kc < 2; ++kc) {
        bf16x8 v;
#pragma unroll
        for (int j = 0; j < 8; ++j) {
            int k = kc * 32 + kg * 8 + j;
            float w = (k < NZV) ? W1[k * H + nbase + col] : 0.f;
            v[j] = (short)f2bf(w);
        }
        w1f[kc] = v;
    }
#pragma unroll
    for (int kc = 0; kc < 4; ++kc) {
        bf16x8 v;
#pragma unroll
        for (int j = 0; j < 8; ++j) {
            int k = kc * 32 + kg * 8 + j;
            v[j] = (short)f2bf(W2[k * H + nbase + col]);
        }
        w2f[kc] = v;
    }
    {   // W3^T A-frag for 16x16x16, K-window = this wave's 16 h2 cols
        bf16x4 v;
#pragma unroll
        for (int j = 0; j < 4; ++j)
            v[j] = (short)f2bf((col < NY) ? W3[(nbase + kg * 4 + j) * NY + col] : 0.f);
        w3a = v;
    }

#define LOAD_UWIN(BI, T0)                                                              \
    if (wid == 1) {                                                                    \
        const float* usrc = u_g + (size_t)(b0 + (lane & 15)) * (T_STEPS * NU)          \
                            + (size_t)((T0) + (lane >> 4)) * NU;                       \
        _Pragma("unroll")                                                              \
        for (int k_ = 0; k_ < 4; ++k_)                                                 \
            __builtin_amdgcn_global_load_lds(                                          \
                (const __attribute__((address_space(1))) unsigned*)(usrc + k_ * 16),   \
                (__attribute__((address_space(3))) unsigned*)(&ubuf[BI][k_ * 4][0][0]),\
                16, 0, 0);                                                             \
    }

    // ---- init z state + first u window ----
    {
        unsigned short* zs = &zbuf[0][0][0];
        for (int i = tid; i < 2 * 16 * ZSTR; i += 512) zs[i] = 0;
        __syncthreads();
        for (int i = tid; i < 16 * NZV; i += 512) {
            int r = i / NZV, c = i - r * NZV;
            zbuf[0][r][c] = f2bf(z0_g[(size_t)(b0 + r) * NZV + c]);
        }
        LOAD_UWIN(0, 0)
        __syncthreads();
    }

    bf16x8 za0, za1l;
    int t = 0;

    // ---- peel t=0: real z0 y-slot (no bypass), wide shift ----
    {
        bf16x8 pza0 = *(const bf16x8*)&zbuf[0][col][kg * 8];
        bf16x8 pza1 = *(const bf16x8*)&zbuf[0][col][32 + kg * 8];
        f32x4 c1 = b1t;
        c1 = MFMA32(w1f[0], pza0, c1, 0, 0, 0);
        c1 = MFMA32(w1f[1], pza1, c1, 0, 0, 0);
        unsigned p01 = cvt_pk_bf16(tanh_fast(c1[0]), tanh_fast(c1[1]));
        unsigned p23 = cvt_pk_bf16(tanh_fast(c1[2]), tanh_fast(c1[3]));
        *(uint2v*)&h1s[col][nbase + kg * 4] = uint2v{p01, p23};
        if (wid == 7) {   // wide shift 8..39 -> 0..31 (moves z0's y-slot), 44..59 -> 40..55
            bf16x4 m0 = *(const bf16x4*)&zbuf[0][urow][8 + 8 * uc];
            bf16x4 m1 = *(const bf16x4*)&zbuf[0][urow][12 + 8 * uc];
            bf16x4 m2 = *(const bf16x4*)&zbuf[0][urow][44 + 4 * uc];
            *(bf16x4*)&zbuf[1][urow][8 * uc]      = m0;
            *(bf16x4*)&zbuf[1][urow][8 * uc + 4]  = m1;
            *(bf16x4*)&zbuf[1][urow][40 + 4 * uc] = m2;
            zbuf[1][urow][56 + uc] = f2bf(ubuf[0][0][urow][uc]);
        }
        __syncthreads();   // B1
        bf16x8 ha0 = *(const bf16x8*)&h1s[col][0 * 32 + kg * 8];
        bf16x8 ha1 = *(const bf16x8*)&h1s[col][1 * 32 + kg * 8];
        bf16x8 ha2 = *(const bf16x8*)&h1s[col][2 * 32 + kg * 8];
        bf16x8 ha3 = *(const bf16x8*)&h1s[col][3 * 32 + kg * 8];
        za0  = *(const bf16x8*)&zbuf[1][col][kg * 8];        // preload for t=1
        za1l = *(const bf16x8*)&zbuf[1][col][32 + kg * 8];
        f32x4 a0 = b2t;
        f32x4 a1 = { 0.f, 0.f, 0.f, 0.f };
        a0 = MFMA32(w2f[0], ha0, a0, 0, 0, 0);
        a1 = MFMA32(w2f[1], ha1, a1, 0, 0, 0);
        a0 = MFMA32(w2f[2], ha2, a0, 0, 0, 0);
        a1 = MFMA32(w2f[3], ha3, a1, 0, 0, 0);
        f32x4 c2 = a0 + a1;
        U2 p; p.u[0] = cvt_pk_bf16(tanh_fast(c2[0]), tanh_fast(c2[1]));
        p.u[1]       = cvt_pk_bf16(tanh_fast(c2[2]), tanh_fast(c2[3]));
        f32x4 yp = (wid == 0) ? b3t : f32x4{0.f, 0.f, 0.f, 0.f};
        yp = gemm3_one(w3a, p.v, yp);
        if (kg < 2) ypart[wid][lane] = yp;
        __syncthreads();   // B2
        t = 1;
    }

    // ---- main body: 2 barriers/step; P = t&1 compile-time ----
#define BODY(P)                                                                         \
    {                                                                                   \
        /* finalize y(t-1) from 8 partials (kg<2 lanes; 4KB/wave LDS) */                \
        f32x4 y_ = { 0.f, 0.f, 0.f, 0.f };                                              \
        unsigned d0 = 0, d1 = 0;                                                        \
        if (kg < 2) {                                                                   \
            y_ = ypart[0][lane] + ypart[1][lane] + ypart[2][lane] + ypart[3][lane]      \
               + ypart[4][lane] + ypart[5][lane] + ypart[6][lane] + ypart[7][lane];     \
            d0 = cvt_pk_bf16(y_[0], y_[1]);                                             \
            d1 = cvt_pk_bf16(y_[2], y_[3]);                                             \
        }                                                                               \
        unsigned o0 = swz16(d0);                                                        \
        unsigned o1 = swz16(d1);                                                        \
        U4 zb_; zb_.u[0] = d0; zb_.u[1] = d1; zb_.u[2] = o0; zb_.u[3] = o1;             \
        bf16x8 za1 = (kg == 0) ? zb_.v : za1l;   /* K=32..39 = y(t-1) in registers */   \
        if (wid == 1 && kg < 2) {                                                       \
            *(f32x4*)&ybuf[(t - 1) & 31][col][kg * 4] = y_;                             \
            *(uint2v*)&zbuf[(P) ^ 1][col][24 + kg * 4] = uint2v{d0, d1};                \
        }                                                                               \
        /* GEMM1 on this wave's 16 cols */                                              \
        f32x4 c1 = b1t;                                                                 \
        c1 = MFMA32(w1f[0], za0, c1, 0, 0, 0);                                          \
        c1 = MFMA32(w1f[1], za1, c1, 0, 0, 0);                                          \
        unsigned p01 = cvt_pk_bf16(tanh_fast(c1[0]), tanh_fast(c1[1]));                 \
        unsigned p23 = cvt_pk_bf16(tanh_fast(c1[2]), tanh_fast(c1[3]));                 \
        *(uint2v*)&h1s[col][nbase + kg * 4] = uint2v{p01, p23};                         \
        if (wid == 7) {   /* narrow shift 8..31 -> 0..23; 44..59 -> 40..55; u insert */ \
            if (uc < 3) {                                                               \
                bf16x4 m0 = *(const bf16x4*)&zbuf[P][urow][8 + 8 * uc];                 \
                bf16x4 m1 = *(const bf16x4*)&zbuf[P][urow][12 + 8 * uc];                \
                *(bf16x4*)&zbuf[(P) ^ 1][urow][8 * uc]     = m0;                        \
                *(bf16x4*)&zbuf[(P) ^ 1][urow][8 * uc + 4] = m1;                        \
            }                                                                           \
            bf16x4 m2 = *(const bf16x4*)&zbuf[P][urow][44 + 4 * uc];                    \
            *(bf16x4*)&zbuf[(P) ^ 1][urow][40 + 4 * uc] = m2;                           \
            zbuf[(P) ^ 1][urow][56 + uc] = f2bf(ubuf[(t >> 4) & 1][t & 15][urow][uc]);  \
        }                                                                               \
        __syncthreads();   /* B1: h1 ready; z[nxt] fully final */                       \
        bf16x8 ha0 = *(const bf16x8*)&h1s[col][0 * 32 + kg * 8];                        \
        bf16x8 ha1 = *(const bf16x8*)&h1s[col][1 * 32 + kg * 8];                        \
        bf16x8 ha2 = *(const bf16x8*)&h1s[col][2 * 32 + kg * 8];                        \
        bf16x8 ha3 = *(const bf16x8*)&h1s[col][3 * 32 + kg * 8];                        \
        za0  = *(const bf16x8*)&zbuf[(P) ^ 1][col][kg * 8];        /* preload t+1 */    \
        za1l = *(const bf16x8*)&zbuf[(P) ^ 1][col][32 + kg * 8];                        \
        f32x4 a0 = b2t;                                                                 \
        f32x4 a1 = { 0.f, 0.f, 0.f, 0.f };                                              \
        a0 = MFMA32(w2f[0], ha0, a0, 0, 0, 0);                                          \
        a1 = MFMA32(w2f[1], ha1, a1, 0, 0, 0);                                          \
        a0 = MFMA32(w2f[2], ha2, a0, 0, 0, 0);                                          \
        a1 = MFMA32(w2f[3], ha3, a1, 0, 0, 0);                                          \
        f32x4 c2 = a0 + a1;                                                             \
        U2 p; p.u[0] = cvt_pk_bf16(tanh_fast(c2[0]), tanh_fast(c2[1]));                 \
        p.u[1]       = cvt_pk_bf16(tanh_fast(c2[2]), tanh_fast(c2[3]));                 \
        f32x4 yp = (wid == 0) ? b3t : f32x4{0.f, 0.f, 0.f, 0.f};                        \
        yp = gemm3_one(w3a, p.v, yp);                                                   \
        if (kg < 2) ypart[wid][lane] = yp;                                              \
        __syncthreads();   /* B2: partials + next-z visible */                          \
        ++t;                                                                            \
    }

#define FLUSH(BT)                                                                       \
    if (tid < 256) {                                                                    \
        const f32x4* yp_ = (const f32x4*)&ybuf[((BT) & 31) + ftoff][frow][0];           \
        f32x4 v0 = yp_[0], v1 = yp_[1];                                                 \
        float* op = out + ((size_t)(b0 + frow) * T_STEPS + (BT) + ftoff) * NY;          \
        *(f32x4*)op = v0;                                                               \
        *(f32x4*)(op + 4) = v1;                                                         \
    }

#pragma unroll 1
    for (int it = 0; it < 511; ++it) {
        if ((t & 15) == 1) {
            if (t > 1)
                FLUSH(t - 17)
            if (t + 15 < T_STEPS)
                LOAD_UWIN((((t + 15) >> 4) & 1), t + 15)
        }
        BODY(1)
        BODY(0)
    }
    BODY(1)   // t = 1023
#undef BODY

    // ---- epilogue: finalize y(1023), flush last window (slots 16..31) ----
    {
        if (kg < 2) {
            f32x4 y_ = ypart[0][lane] + ypart[1][lane] + ypart[2][lane] + ypart[3][lane]
                     + ypart[4][lane] + ypart[5][lane] + ypart[6][lane] + ypart[7][lane];
            if (wid == 1)
                *(f32x4*)&ybuf[31][col][kg * 4] = y_;
        }
        __syncthreads();
        if (tid < 256) {
            const f32x4* yp_ = (const f32x4*)&ybuf[16 + ftoff][frow][0];
            f32x4 v0 = yp_[0], v1 = yp_[1];
            float* op = out + ((size_t)(b0 + frow) * T_STEPS + 1008 + ftoff) * NY;
            *(f32x4*)op = v0;
            *(f32x4*)(op + 4) = v1;
        }
    }
#undef FLUSH
#undef LOAD_UWIN
}

extern "C" void kernel_launch(void* const* d_in, const int* in_sizes, int n_in,
                              void* d_out, int out_size, void* d_ws, size_t ws_size,
                              hipStream_t stream) {
    (void)in_sizes; (void)n_in; (void)d_ws; (void)ws_size; (void)out_size;
    const float* u  = (const float*)d_in[0];
    const float* z0 = (const float*)d_in[1];
    const float* W1 = (const float*)d_in[2];
    const float* b1 = (const float*)d_in[3];
    const float* W2 = (const float*)d_in[4];
    const float* b2 = (const float*)d_in[5];
    const float* W3 = (const float*)d_in[6];
    const float* b3 = (const float*)d_in[7];
    float* out = (float*)d_out;

    dim3 grid(8192 / 16);   // 512 blocks x 8 waves; 16 batch rows/block
    dim3 block(512);
    cstr_scan_kernel<<<grid, block, 0, stream>>>(u, z0, W1, b1, W2, b2, W3, b3, out);
}

// Round 12
// 942.544 us; speedup vs baseline: 1.2976x; 1.2976x over previous
//
#include <hip/hip_runtime.h>

#define T_STEPS 1024
#define NZV 60          // valid z width
#define H 128
#define NY 8
#define NU 4
#define ZSTR 72         // padded LDS stride (shorts) for z
#define HSTR 136        // padded LDS stride (shorts) for h1

typedef __attribute__((ext_vector_type(8))) short bf16x8;
typedef __attribute__((ext_vector_type(4))) short bf16x4;
typedef __attribute__((ext_vector_type(4))) float f32x4;
typedef __attribute__((ext_vector_type(2))) unsigned uint2v;

union U4 { unsigned u[4]; bf16x8 v; };
union U2 { unsigned u[2]; bf16x4 v; };

__device__ __forceinline__ unsigned short f2bf(float x) {
    unsigned u = __float_as_uint(x);
    u += 0x7FFFu + ((u >> 16) & 1u);
    return (unsigned short)(u >> 16);
}

__device__ __forceinline__ unsigned cvt_pk_bf16(float lo, float hi) {
    unsigned r;
    asm("v_cvt_pk_bf16_f32 %0, %1, %2" : "=v"(r) : "v"(lo), "v"(hi));
    return r;
}

__device__ __forceinline__ unsigned swz16(unsigned v) {
    return (unsigned)__builtin_amdgcn_ds_swizzle((int)v, 0x401F);  // xor lane^16
}

// tanh(x) = 1 - 2/(exp(2x)+1); exp2 saturates so no clamp needed.
__device__ __forceinline__ float tanh_fast(float x) {
    float e = __builtin_amdgcn_exp2f(x * 2.8853900817779268f);
    return fmaf(-2.0f, __builtin_amdgcn_rcpf(e + 1.0f), 1.0f);
}

#define MFMA32 __builtin_amdgcn_mfma_f32_16x16x32_bf16

// two chained 16x16x16 bf16 MFMAs (partial GEMM3 over this wave's 32 hid cols).
// inline asm => compiler hazard recognizer blind: s_nop 1 guards VALU->MFMA src,
// s_nop 7 x2 guards MFMA D -> ds_write read.
__device__ __forceinline__ f32x4 gemm3_pair(bf16x4 a0, bf16x4 b0,
                                            bf16x4 a1, bf16x4 b1, f32x4 c) {
    asm("s_nop 1\n\t"
        "v_mfma_f32_16x16x16_bf16 %0, %1, %2, %0\n\t"
        "v_mfma_f32_16x16x16_bf16 %0, %3, %4, %0\n\t"
        "s_nop 7\n\t"
        "s_nop 7"
        : "+v"(c) : "v"(a0), "v"(b0), "v"(a1), "v"(b1));
    return c;
}

__global__ __launch_bounds__(256, 2)
void cstr_scan_kernel(const float* __restrict__ u_g, const float* __restrict__ z0_g,
                      const float* __restrict__ W1, const float* __restrict__ b1,
                      const float* __restrict__ W2, const float* __restrict__ b2,
                      const float* __restrict__ W3, const float* __restrict__ b3,
                      float* __restrict__ out) {
    __shared__ unsigned short zbuf[2][16][ZSTR];
    __shared__ unsigned short h1s[16][HSTR];
    __shared__ f32x4 ypart[4][64];           // per-wave GEMM3 partials (y^T frags)
    __shared__ float ybuf[32][16][NY];       // 32-deep y ring, flushed 16/step
    __shared__ float ubuf[2][16][16][NU];    // u windows (DMA'd)

    const int tid   = threadIdx.x;
    const int wid   = tid >> 6;          // 0..3
    const int lane  = tid & 63;
    const int b0    = blockIdx.x * 16;   // batch row base
    const int col   = lane & 15;         // batch row (swapped C-frags)
    const int kg    = lane >> 4;         // 0..3
    const int urow  = lane >> 2;         // shift row
    const int uc    = lane & 3;
    const int nbase = wid * 32;          // this wave's hidden-col base
    const int frow  = tid >> 4;          // flush: batch row
    const int ftoff = tid & 15;          // flush: time offset

    // ---- preload weight fragments (A-operands of swapped MFMAs) ----
    bf16x8 w1f[2][2], w2f[4][2];
    bf16x4 w3a0, w3a1;
    f32x4 b1t[2], b2t[2], b3t;
#pragma unroll
    for (int nl = 0; nl < 2; ++nl)
#pragma unroll
        for (int r = 0; r < 4; ++r) {
            b1t[nl][r] = b1[nbase + nl * 16 + kg * 4 + r];
            b2t[nl][r] = b2[nbase + nl * 16 + kg * 4 + r];
        }
#pragma unroll
    for (int r = 0; r < 4; ++r) {
        int m = kg * 4 + r;
        b3t[r] = (m < NY) ? b3[m] : 0.f;
    }
#pragma unroll
    for (int kc = 0; kc < 2; ++kc)
#pragma unroll
        for (int nl = 0; nl < 2; ++nl) {
            bf16x8 v;
#pragma unroll
            for (int j = 0; j < 8; ++j) {
                int k = kc * 32 + kg * 8 + j;
                float w = (k < NZV) ? W1[k * H + nbase + nl * 16 + col] : 0.f;
                v[j] = (short)f2bf(w);
            }
            w1f[kc][nl] = v;
        }
#pragma unroll
    for (int kc = 0; kc < 4; ++kc)
#pragma unroll
        for (int nl = 0; nl < 2; ++nl) {
            bf16x8 v;
#pragma unroll
            for (int j = 0; j < 8; ++j) {
                int k = kc * 32 + kg * 8 + j;
                v[j] = (short)f2bf(W2[k * H + nbase + nl * 16 + col]);
            }
            w2f[kc][nl] = v;
        }
    {   // W3^T A-frags for 16x16x16: A[m=ny=col][k local] per nl window
        bf16x4 v0, v1;
#pragma unroll
        for (int j = 0; j < 4; ++j) {
            v0[j] = (short)f2bf((col < NY) ? W3[(nbase + 0  + kg * 4 + j) * NY + col] : 0.f);
            v1[j] = (short)f2bf((col < NY) ? W3[(nbase + 16 + kg * 4 + j) * NY + col] : 0.f);
        }
        w3a0 = v0; w3a1 = v1;
    }

#define LOAD_UWIN(BI, T0)                                                              \
    if (wid == 1) {                                                                    \
        const float* usrc = u_g + (size_t)(b0 + (lane & 15)) * (T_STEPS * NU)          \
                            + (size_t)((T0) + (lane >> 4)) * NU;                       \
        _Pragma("unroll")                                                              \
        for (int k_ = 0; k_ < 4; ++k_)                                                 \
            __builtin_amdgcn_global_load_lds(                                          \
                (const __attribute__((address_space(1))) unsigned*)(usrc + k_ * 16),   \
                (__attribute__((address_space(3))) unsigned*)(&ubuf[BI][k_ * 4][0][0]),\
                16, 0, 0);                                                             \
    }

    // ---- init z state + first u window ----
    {
        unsigned short* zs = &zbuf[0][0][0];
        for (int i = tid; i < 2 * 16 * ZSTR; i += 256) zs[i] = 0;
        __syncthreads();
        for (int i = tid; i < 16 * NZV; i += 256) {
            int r = i / NZV, c = i - r * NZV;
            zbuf[0][r][c] = f2bf(z0_g[(size_t)(b0 + r) * NZV + c]);
        }
        LOAD_UWIN(0, 0)
        __syncthreads();
    }

    bf16x8 za0, za1l;
    int t = 0;

    // ---- peel t=0: real z0 y-slot (no bypass), wide shift ----
    {
        bf16x8 pza0 = *(const bf16x8*)&zbuf[0][col][kg * 8];
        bf16x8 pza1 = *(const bf16x8*)&zbuf[0][col][32 + kg * 8];
#pragma unroll
        for (int nl = 0; nl < 2; ++nl) {
            f32x4 c1 = b1t[nl];
            c1 = MFMA32(w1f[0][nl], pza0, c1, 0, 0, 0);
            c1 = MFMA32(w1f[1][nl], pza1, c1, 0, 0, 0);
            unsigned p01 = cvt_pk_bf16(tanh_fast(c1[0]), tanh_fast(c1[1]));
            unsigned p23 = cvt_pk_bf16(tanh_fast(c1[2]), tanh_fast(c1[3]));
            *(uint2v*)&h1s[col][nbase + nl * 16 + kg * 4] = uint2v{p01, p23};
        }
        if (wid == 3) {   // wide shift 8..39 -> 0..31 (moves z0's y-slot), 44..59 -> 40..55
            bf16x4 m0 = *(const bf16x4*)&zbuf[0][urow][8 + 8 * uc];
            bf16x4 m1 = *(const bf16x4*)&zbuf[0][urow][12 + 8 * uc];
            bf16x4 m2 = *(const bf16x4*)&zbuf[0][urow][44 + 4 * uc];
            *(bf16x4*)&zbuf[1][urow][8 * uc]      = m0;
            *(bf16x4*)&zbuf[1][urow][8 * uc + 4]  = m1;
            *(bf16x4*)&zbuf[1][urow][40 + 4 * uc] = m2;
            zbuf[1][urow][56 + uc] = f2bf(ubuf[0][0][urow][uc]);
        }
        __syncthreads();   // B1
        bf16x8 ha0 = *(const bf16x8*)&h1s[col][0 * 32 + kg * 8];
        bf16x8 ha1 = *(const bf16x8*)&h1s[col][1 * 32 + kg * 8];
        bf16x8 ha2 = *(const bf16x8*)&h1s[col][2 * 32 + kg * 8];
        bf16x8 ha3 = *(const bf16x8*)&h1s[col][3 * 32 + kg * 8];
        za0  = *(const bf16x8*)&zbuf[1][col][kg * 8];        // preload for t=1
        za1l = *(const bf16x8*)&zbuf[1][col][32 + kg * 8];
        bf16x4 pb0, pb1;
#pragma unroll
        for (int nl = 0; nl < 2; ++nl) {
            f32x4 a0 = b2t[nl];
            f32x4 a1 = { 0.f, 0.f, 0.f, 0.f };
            a0 = MFMA32(w2f[0][nl], ha0, a0, 0, 0, 0);
            a1 = MFMA32(w2f[1][nl], ha1, a1, 0, 0, 0);
            a0 = MFMA32(w2f[2][nl], ha2, a0, 0, 0, 0);
            a1 = MFMA32(w2f[3][nl], ha3, a1, 0, 0, 0);
            f32x4 c2 = a0 + a1;
            U2 p; p.u[0] = cvt_pk_bf16(tanh_fast(c2[0]), tanh_fast(c2[1]));
            p.u[1]       = cvt_pk_bf16(tanh_fast(c2[2]), tanh_fast(c2[3]));
            if (nl == 0) pb0 = p.v; else pb1 = p.v;
        }
        f32x4 yp = (wid == 0) ? b3t : f32x4{0.f, 0.f, 0.f, 0.f};
        yp = gemm3_pair(w3a0, pb0, w3a1, pb1, yp);
        ypart[wid][lane] = yp;
        __syncthreads();   // B2
        t = 1;
    }

    // ---- main body: 2 barriers/step; P = t&1 compile-time ----
#define BODY(P)                                                                         \
    {                                                                                   \
        /* finalize y(t-1) from partials (all waves; needed for za1 bypass) */          \
        f32x4 y_ = ypart[0][lane] + ypart[1][lane] + ypart[2][lane] + ypart[3][lane];   \
        unsigned d0 = cvt_pk_bf16(y_[0], y_[1]);                                        \
        unsigned d1 = cvt_pk_bf16(y_[2], y_[3]);                                        \
        unsigned o0 = swz16(d0);                                                        \
        unsigned o1 = swz16(d1);                                                        \
        U4 zb_; zb_.u[0] = d0; zb_.u[1] = d1; zb_.u[2] = o0; zb_.u[3] = o1;             \
        bf16x8 za1 = (kg == 0) ? zb_.v : za1l;   /* K=32..39 = y(t-1) in registers */   \
        if (wid == 1 && kg < 2) {                                                       \
            *(f32x4*)&ybuf[(t - 1) & 31][col][kg * 4] = y_;                             \
            *(uint2v*)&zbuf[(P) ^ 1][col][24 + kg * 4] = uint2v{d0, d1};                \
        }                                                                               \
        _Pragma("unroll")                                                               \
        for (int nl = 0; nl < 2; ++nl) {                                                \
            f32x4 c1 = b1t[nl];                                                         \
            c1 = MFMA32(w1f[0][nl], za0, c1, 0, 0, 0);                                  \
            c1 = MFMA32(w1f[1][nl], za1, c1, 0, 0, 0);                                  \
            unsigned p01 = cvt_pk_bf16(tanh_fast(c1[0]), tanh_fast(c1[1]));             \
            unsigned p23 = cvt_pk_bf16(tanh_fast(c1[2]), tanh_fast(c1[3]));             \
            *(uint2v*)&h1s[col][nbase + nl * 16 + kg * 4] = uint2v{p01, p23};           \
        }                                                                               \
        if (wid == 3) {   /* narrow shift 8..31 -> 0..23; 44..59 -> 40..55; u insert */ \
            if (uc < 3) {                                                               \
                bf16x4 m0 = *(const bf16x4*)&zbuf[P][urow][8 + 8 * uc];                 \
                bf16x4 m1 = *(const bf16x4*)&zbuf[P][urow][12 + 8 * uc];                \
                *(bf16x4*)&zbuf[(P) ^ 1][urow][8 * uc]     = m0;                        \
                *(bf16x4*)&zbuf[(P) ^ 1][urow][8 * uc + 4] = m1;                        \
            }                                                                           \
            bf16x4 m2 = *(const bf16x4*)&zbuf[P][urow][44 + 4 * uc];                    \
            *(bf16x4*)&zbuf[(P) ^ 1][urow][40 + 4 * uc] = m2;                           \
            zbuf[(P) ^ 1][urow][56 + uc] = f2bf(ubuf[(t >> 4) & 1][t & 15][urow][uc]);  \
        }                                                                               \
        __syncthreads();   /* B1: h1 ready; z[nxt] fully final */                       \
        bf16x8 ha0 = *(const bf16x8*)&h1s[col][0 * 32 + kg * 8];                        \
        bf16x8 ha1 = *(const bf16x8*)&h1s[col][1 * 32 + kg * 8];                        \
        bf16x8 ha2 = *(const bf16x8*)&h1s[col][2 * 32 + kg * 8];                        \
        bf16x8 ha3 = *(const bf16x8*)&h1s[col][3 * 32 + kg * 8];                        \
        za0  = *(const bf16x8*)&zbuf[(P) ^ 1][col][kg * 8];        /* preload t+1 */    \
        za1l = *(const bf16x8*)&zbuf[(P) ^ 1][col][32 + kg * 8];                        \
        __builtin_amdgcn_s_setprio(1);                                                  \
        bf16x4 pb0, pb1;                                                                \
        _Pragma("unroll")                                                               \
        for (int nl = 0; nl < 2; ++nl) {                                                \
            f32x4 a0 = b2t[nl];                                                         \
            f32x4 a1 = { 0.f, 0.f, 0.f, 0.f };                                          \
            a0 = MFMA32(w2f[0][nl], ha0, a0, 0, 0, 0);                                  \
            a1 = MFMA32(w2f[1][nl], ha1, a1, 0, 0, 0);                                  \
            a0 = MFMA32(w2f[2][nl], ha2, a0, 0, 0, 0);                                  \
            a1 = MFMA32(w2f[3][nl], ha3, a1, 0, 0, 0);                                  \
            f32x4 c2 = a0 + a1;                                                         \
            U2 p; p.u[0] = cvt_pk_bf16(tanh_fast(c2[0]), tanh_fast(c2[1]));             \
            p.u[1]       = cvt_pk_bf16(tanh_fast(c2[2]), tanh_fast(c2[3]));             \
            if (nl == 0) pb0 = p.v; else pb1 = p.v;                                     \
        }                                                                               \
        f32x4 yp = (wid == 0) ? b3t : f32x4{0.f, 0.f, 0.f, 0.f};                        \
        yp = gemm3_pair(w3a0, pb0, w3a1, pb1, yp);                                      \
        __builtin_amdgcn_s_setprio(0);                                                  \
        ypart[wid][lane] = yp;                                                          \
        __syncthreads();   /* B2: partials + next-z visible */                          \
        ++t;                                                                            \
    }

#define FLUSH(BT)                                                                       \
    {                                                                                   \
        const f32x4* yp_ = (const f32x4*)&ybuf[((BT) & 31) + ftoff][frow][0];           \
        f32x4 v0 = yp_[0], v1 = yp_[1];                                                 \
        float* op = out + ((size_t)(b0 + frow) * T_STEPS + (BT) + ftoff) * NY;          \
        *(f32x4*)op = v0;                                                               \
        *(f32x4*)(op + 4) = v1;                                                         \
    }

#pragma unroll 1
    for (int it = 0; it < 511; ++it) {
        if ((t & 15) == 1) {
            if (t > 1)
                FLUSH(t - 17)
            if (t + 15 < T_STEPS)
                LOAD_UWIN((((t + 15) >> 4) & 1), t + 15)
        }
        BODY(1)
        BODY(0)
    }
    BODY(1)   // t = 1023
#undef BODY

    // ---- epilogue: finalize y(1023), flush last window (slots 16..31) ----
    {
        if (wid == 1 && kg < 2) {
            f32x4 y_ = ypart[0][lane] + ypart[1][lane] + ypart[2][lane] + ypart[3][lane];
            *(f32x4*)&ybuf[31][col][kg * 4] = y_;
        }
        __syncthreads();
        const f32x4* yp_ = (const f32x4*)&ybuf[16 + ftoff][frow][0];
        f32x4 v0 = yp_[0], v1 = yp_[1];
        float* op = out + ((size_t)(b0 + frow) * T_STEPS + 1008 + ftoff) * NY;
        *(f32x4*)op = v0;
        *(f32x4*)(op + 4) = v1;
    }
#undef FLUSH
#undef LOAD_UWIN
}

extern "C" void kernel_launch(void* const* d_in, const int* in_sizes, int n_in,
                              void* d_out, int out_size, void* d_ws, size_t ws_size,
                              hipStream_t stream) {
    (void)in_sizes; (void)n_in; (void)d_ws; (void)ws_size; (void)out_size;
    const float* u  = (const float*)d_in[0];
    const float* z0 = (const float*)d_in[1];
    const float* W1 = (const float*)d_in[2];
    const float* b1 = (const float*)d_in[3];
    const float* W2 = (const float*)d_in[4];
    const float* b2 = (const float*)d_in[5];
    const float* W3 = (const float*)d_in[6];
    const float* b3 = (const float*)d_in[7];
    float* out = (float*)d_out;

    dim3 grid(8192 / 16);   // 512 blocks x 4 waves; 16 batch rows/block
    dim3 block(256);
    cstr_scan_kernel<<<grid, block, 0, stream>>>(u, z0, W1, b1, W2, b2, W3, b3, out);
}

// Round 13
// 940.531 us; speedup vs baseline: 1.3004x; 1.0021x over previous
//
#include <hip/hip_runtime.h>

#define T_STEPS 1024
#define NZV 60          // valid z width
#define H 128
#define NY 8
#define NU 4
#define ZSTR 72         // padded LDS stride (shorts) for z
#define HSTR 136        // padded LDS stride (shorts) for h1
#define YBSTR 132       // padded per-timestep stride (floats) for ybuf

typedef __attribute__((ext_vector_type(8))) short bf16x8;
typedef __attribute__((ext_vector_type(4))) short bf16x4;
typedef __attribute__((ext_vector_type(4))) float f32x4;
typedef __attribute__((ext_vector_type(2))) unsigned uint2v;

union U4 { unsigned u[4]; bf16x8 v; };
union U2 { unsigned u[2]; bf16x4 v; };

__device__ __forceinline__ unsigned short f2bf(float x) {
    unsigned u = __float_as_uint(x);
    u += 0x7FFFu + ((u >> 16) & 1u);
    return (unsigned short)(u >> 16);
}

__device__ __forceinline__ unsigned cvt_pk_bf16(float lo, float hi) {
    unsigned r;
    asm("v_cvt_pk_bf16_f32 %0, %1, %2" : "=v"(r) : "v"(lo), "v"(hi));
    return r;
}

__device__ __forceinline__ unsigned swz16(unsigned v) {
    return (unsigned)__builtin_amdgcn_ds_swizzle((int)v, 0x401F);  // xor lane^16
}

// tanh(x) = 1 - 2/(exp(2x)+1); exp2 saturates so no clamp needed.
__device__ __forceinline__ float tanh_fast(float x) {
    float e = __builtin_amdgcn_exp2f(x * 2.8853900817779268f);
    return fmaf(-2.0f, __builtin_amdgcn_rcpf(e + 1.0f), 1.0f);
}

#define MFMA32 __builtin_amdgcn_mfma_f32_16x16x32_bf16

// two chained 16x16x16 bf16 MFMAs (partial GEMM3 over this wave's 32 hid cols).
// inline asm => compiler hazard recognizer blind: s_nop 1 guards VALU->MFMA src,
// s_nop 7 x2 guards MFMA D -> ds_write read.
__device__ __forceinline__ f32x4 gemm3_pair(bf16x4 a0, bf16x4 b0,
                                            bf16x4 a1, bf16x4 b1, f32x4 c) {
    asm("s_nop 1\n\t"
        "v_mfma_f32_16x16x16_bf16 %0, %1, %2, %0\n\t"
        "v_mfma_f32_16x16x16_bf16 %0, %3, %4, %0\n\t"
        "s_nop 7\n\t"
        "s_nop 7"
        : "+v"(c) : "v"(a0), "v"(b0), "v"(a1), "v"(b1));
    return c;
}

__global__ __launch_bounds__(256, 2)
void cstr_scan_kernel(const float* __restrict__ u_g, const float* __restrict__ z0_g,
                      const float* __restrict__ W1, const float* __restrict__ b1,
                      const float* __restrict__ W2, const float* __restrict__ b2,
                      const float* __restrict__ W3, const float* __restrict__ b3,
                      float* __restrict__ out) {
    __shared__ unsigned short zbuf[2][16][ZSTR];
    __shared__ unsigned short h1s[16][HSTR];
    __shared__ f32x4 ypart[4][72];           // per-wave GEMM3 partials, bank-padded idx
    __shared__ float ybuf[32 * YBSTR];       // 32-deep y ring (stride 132 f32/slot)
    __shared__ float ubuf[2][16][16][NU];    // u windows (DMA'd)

    const int tid   = threadIdx.x;
    const int wid   = tid >> 6;          // 0..3
    const int lane  = tid & 63;
    const int b0    = blockIdx.x * 16;   // batch row base
    const int col   = lane & 15;         // batch row (swapped C-frags)
    const int kg    = lane >> 4;         // 0..3
    const int urow  = lane >> 2;         // shift row
    const int uc    = lane & 3;
    const int nbase = wid * 32;          // this wave's hidden-col base
    const int frow  = tid >> 4;          // flush: batch row
    const int ftoff = tid & 15;          // flush: time offset
    const int ypIdx = lane + (lane >> 3);  // bank-conflict-free f32x4 slot (max 70)

    // ---- preload weight fragments (A-operands of swapped MFMAs) ----
    bf16x8 w1f[2][2], w2f[4][2];
    bf16x4 w3a0, w3a1;
    f32x4 b1t[2], b2t[2], b3t;
#pragma unroll
    for (int nl = 0; nl < 2; ++nl)
#pragma unroll
        for (int r = 0; r < 4; ++r) {
            b1t[nl][r] = b1[nbase + nl * 16 + kg * 4 + r];
            b2t[nl][r] = b2[nbase + nl * 16 + kg * 4 + r];
        }
#pragma unroll
    for (int r = 0; r < 4; ++r) {
        int m = kg * 4 + r;
        b3t[r] = (m < NY) ? b3[m] : 0.f;
    }
#pragma unroll
    for (int kc = 0; kc < 2; ++kc)
#pragma unroll
        for (int nl = 0; nl < 2; ++nl) {
            bf16x8 v;
#pragma unroll
            for (int j = 0; j < 8; ++j) {
                int k = kc * 32 + kg * 8 + j;
                float w = (k < NZV) ? W1[k * H + nbase + nl * 16 + col] : 0.f;
                v[j] = (short)f2bf(w);
            }
            w1f[kc][nl] = v;
        }
#pragma unroll
    for (int kc = 0; kc < 4; ++kc)
#pragma unroll
        for (int nl = 0; nl < 2; ++nl) {
            bf16x8 v;
#pragma unroll
            for (int j = 0; j < 8; ++j) {
                int k = kc * 32 + kg * 8 + j;
                v[j] = (short)f2bf(W2[k * H + nbase + nl * 16 + col]);
            }
            w2f[kc][nl] = v;
        }
    {   // W3^T A-frags for 16x16x16: A[m=ny=col][k local] per nl window
        bf16x4 v0, v1;
#pragma unroll
        for (int j = 0; j < 4; ++j) {
            v0[j] = (short)f2bf((col < NY) ? W3[(nbase + 0  + kg * 4 + j) * NY + col] : 0.f);
            v1[j] = (short)f2bf((col < NY) ? W3[(nbase + 16 + kg * 4 + j) * NY + col] : 0.f);
        }
        w3a0 = v0; w3a1 = v1;
    }

#define LOAD_UWIN(BI, T0)                                                              \
    if (wid == 1) {                                                                    \
        const float* usrc = u_g + (size_t)(b0 + (lane & 15)) * (T_STEPS * NU)          \
                            + (size_t)((T0) + (lane >> 4)) * NU;                       \
        _Pragma("unroll")                                                              \
        for (int k_ = 0; k_ < 4; ++k_)                                                 \
            __builtin_amdgcn_global_load_lds(                                          \
                (const __attribute__((address_space(1))) unsigned*)(usrc + k_ * 16),   \
                (__attribute__((address_space(3))) unsigned*)(&ubuf[BI][k_ * 4][0][0]),\
                16, 0, 0);                                                             \
    }

    // ---- init z state + first u window ----
    {
        unsigned short* zs = &zbuf[0][0][0];
        for (int i = tid; i < 2 * 16 * ZSTR; i += 256) zs[i] = 0;
        __syncthreads();
        for (int i = tid; i < 16 * NZV; i += 256) {
            int r = i / NZV, c = i - r * NZV;
            zbuf[0][r][c] = f2bf(z0_g[(size_t)(b0 + r) * NZV + c]);
        }
        LOAD_UWIN(0, 0)
        __syncthreads();
    }

    bf16x8 za0, za1l;
    int t = 0;

    // ---- peel t=0: real z0 y-slot (no bypass), wide shift ----
    {
        bf16x8 pza0 = *(const bf16x8*)&zbuf[0][col][kg * 8];
        bf16x8 pza1 = *(const bf16x8*)&zbuf[0][col][32 + kg * 8];
#pragma unroll
        for (int nl = 0; nl < 2; ++nl) {
            f32x4 c1 = b1t[nl];
            c1 = MFMA32(w1f[0][nl], pza0, c1, 0, 0, 0);
            c1 = MFMA32(w1f[1][nl], pza1, c1, 0, 0, 0);
            unsigned p01 = cvt_pk_bf16(tanh_fast(c1[0]), tanh_fast(c1[1]));
            unsigned p23 = cvt_pk_bf16(tanh_fast(c1[2]), tanh_fast(c1[3]));
            *(uint2v*)&h1s[col][nbase + nl * 16 + kg * 4] = uint2v{p01, p23};
        }
        if (wid == 3) {   // wide shift 8..39 -> 0..31 (moves z0's y-slot), 44..59 -> 40..55
            bf16x4 m0 = *(const bf16x4*)&zbuf[0][urow][8 + 8 * uc];
            bf16x4 m1 = *(const bf16x4*)&zbuf[0][urow][12 + 8 * uc];
            bf16x4 m2 = *(const bf16x4*)&zbuf[0][urow][44 + 4 * uc];
            *(bf16x4*)&zbuf[1][urow][8 * uc]      = m0;
            *(bf16x4*)&zbuf[1][urow][8 * uc + 4]  = m1;
            *(bf16x4*)&zbuf[1][urow][40 + 4 * uc] = m2;
            zbuf[1][urow][56 + uc] = f2bf(ubuf[0][0][urow][uc]);
        }
        __syncthreads();   // B1
        bf16x8 ha0 = *(const bf16x8*)&h1s[col][0 * 32 + kg * 8];
        bf16x8 ha1 = *(const bf16x8*)&h1s[col][1 * 32 + kg * 8];
        bf16x8 ha2 = *(const bf16x8*)&h1s[col][2 * 32 + kg * 8];
        bf16x8 ha3 = *(const bf16x8*)&h1s[col][3 * 32 + kg * 8];
        za0  = *(const bf16x8*)&zbuf[1][col][kg * 8];        // preload for t=1
        za1l = *(const bf16x8*)&zbuf[1][col][32 + kg * 8];
        bf16x4 pb0, pb1;
#pragma unroll
        for (int nl = 0; nl < 2; ++nl) {
            f32x4 a0 = b2t[nl];
            f32x4 a1 = { 0.f, 0.f, 0.f, 0.f };
            a0 = MFMA32(w2f[0][nl], ha0, a0, 0, 0, 0);
            a1 = MFMA32(w2f[1][nl], ha1, a1, 0, 0, 0);
            a0 = MFMA32(w2f[2][nl], ha2, a0, 0, 0, 0);
            a1 = MFMA32(w2f[3][nl], ha3, a1, 0, 0, 0);
            f32x4 c2 = a0 + a1;
            U2 p; p.u[0] = cvt_pk_bf16(tanh_fast(c2[0]), tanh_fast(c2[1]));
            p.u[1]       = cvt_pk_bf16(tanh_fast(c2[2]), tanh_fast(c2[3]));
            if (nl == 0) pb0 = p.v; else pb1 = p.v;
        }
        f32x4 yp = (wid == 0) ? b3t : f32x4{0.f, 0.f, 0.f, 0.f};
        yp = gemm3_pair(w3a0, pb0, w3a1, pb1, yp);
        ypart[wid][ypIdx] = yp;
        __syncthreads();   // B2
        t = 1;
    }

    // ---- main body: 2 barriers/step; P = t&1 compile-time ----
#define BODY(P)                                                                         \
    {                                                                                   \
        /* finalize y(t-1) from partials (all waves; needed for za1 bypass) */          \
        f32x4 y_ = ypart[0][ypIdx] + ypart[1][ypIdx] + ypart[2][ypIdx] + ypart[3][ypIdx];\
        unsigned d0 = cvt_pk_bf16(y_[0], y_[1]);                                        \
        unsigned d1 = cvt_pk_bf16(y_[2], y_[3]);                                        \
        unsigned o0 = swz16(d0);                                                        \
        unsigned o1 = swz16(d1);                                                        \
        U4 zb_; zb_.u[0] = d0; zb_.u[1] = d1; zb_.u[2] = o0; zb_.u[3] = o1;             \
        bf16x8 za1 = (kg == 0) ? zb_.v : za1l;   /* K=32..39 = y(t-1) in registers */   \
        if (wid == 1 && kg < 2) {                                                       \
            *(f32x4*)&ybuf[((t - 1) & 31) * YBSTR + col * 8 + kg * 4] = y_;             \
            *(uint2v*)&zbuf[(P) ^ 1][col][24 + kg * 4] = uint2v{d0, d1};                \
        }                                                                               \
        _Pragma("unroll")                                                               \
        for (int nl = 0; nl < 2; ++nl) {                                                \
            f32x4 c1 = b1t[nl];                                                         \
            c1 = MFMA32(w1f[0][nl], za0, c1, 0, 0, 0);                                  \
            c1 = MFMA32(w1f[1][nl], za1, c1, 0, 0, 0);                                  \
            unsigned p01 = cvt_pk_bf16(tanh_fast(c1[0]), tanh_fast(c1[1]));             \
            unsigned p23 = cvt_pk_bf16(tanh_fast(c1[2]), tanh_fast(c1[3]));             \
            *(uint2v*)&h1s[col][nbase + nl * 16 + kg * 4] = uint2v{p01, p23};           \
        }                                                                               \
        if (wid == 3) {   /* narrow shift 8..31 -> 0..23; 44..59 -> 40..55; u insert */ \
            if (uc < 3) {                                                               \
                bf16x4 m0 = *(const bf16x4*)&zbuf[P][urow][8 + 8 * uc];                 \
                bf16x4 m1 = *(const bf16x4*)&zbuf[P][urow][12 + 8 * uc];                \
                *(bf16x4*)&zbuf[(P) ^ 1][urow][8 * uc]     = m0;                        \
                *(bf16x4*)&zbuf[(P) ^ 1][urow][8 * uc + 4] = m1;                        \
            }                                                                           \
            bf16x4 m2 = *(const bf16x4*)&zbuf[P][urow][44 + 4 * uc];                    \
            *(bf16x4*)&zbuf[(P) ^ 1][urow][40 + 4 * uc] = m2;                           \
            zbuf[(P) ^ 1][urow][56 + uc] = f2bf(ubuf[(t >> 4) & 1][t & 15][urow][uc]);  \
        }                                                                               \
        __syncthreads();   /* B1: h1 ready; z[nxt] fully final */                       \
        bf16x8 ha0 = *(const bf16x8*)&h1s[col][0 * 32 + kg * 8];                        \
        bf16x8 ha1 = *(const bf16x8*)&h1s[col][1 * 32 + kg * 8];                        \
        bf16x8 ha2 = *(const bf16x8*)&h1s[col][2 * 32 + kg * 8];                        \
        bf16x8 ha3 = *(const bf16x8*)&h1s[col][3 * 32 + kg * 8];                        \
        za0  = *(const bf16x8*)&zbuf[(P) ^ 1][col][kg * 8];        /* preload t+1 */    \
        za1l = *(const bf16x8*)&zbuf[(P) ^ 1][col][32 + kg * 8];                        \
        __builtin_amdgcn_s_setprio(1);                                                  \
        bf16x4 pb0, pb1;                                                                \
        _Pragma("unroll")                                                               \
        for (int nl = 0; nl < 2; ++nl) {                                                \
            f32x4 a0 = b2t[nl];                                                         \
            f32x4 a1 = { 0.f, 0.f, 0.f, 0.f };                                          \
            a0 = MFMA32(w2f[0][nl], ha0, a0, 0, 0, 0);                                  \
            a1 = MFMA32(w2f[1][nl], ha1, a1, 0, 0, 0);                                  \
            a0 = MFMA32(w2f[2][nl], ha2, a0, 0, 0, 0);                                  \
            a1 = MFMA32(w2f[3][nl], ha3, a1, 0, 0, 0);                                  \
            f32x4 c2 = a0 + a1;                                                         \
            U2 p; p.u[0] = cvt_pk_bf16(tanh_fast(c2[0]), tanh_fast(c2[1]));             \
            p.u[1]       = cvt_pk_bf16(tanh_fast(c2[2]), tanh_fast(c2[3]));             \
            if (nl == 0) pb0 = p.v; else pb1 = p.v;                                     \
        }                                                                               \
        f32x4 yp = (wid == 0) ? b3t : f32x4{0.f, 0.f, 0.f, 0.f};                        \
        yp = gemm3_pair(w3a0, pb0, w3a1, pb1, yp);                                      \
        __builtin_amdgcn_s_setprio(0);                                                  \
        ypart[wid][ypIdx] = yp;                                                         \
        __syncthreads();   /* B2: partials + next-z visible */                          \
        ++t;                                                                            \
    }

#define FLUSH(BT)                                                                       \
    {                                                                                   \
        const f32x4* yp_ = (const f32x4*)&ybuf[(((BT) & 31) + ftoff) * YBSTR + frow * 8];\
        f32x4 v0 = yp_[0], v1 = yp_[1];                                                 \
        float* op = out + ((size_t)(b0 + frow) * T_STEPS + (BT) + ftoff) * NY;          \
        *(f32x4*)op = v0;                                                               \
        *(f32x4*)(op + 4) = v1;                                                         \
    }

#pragma unroll 1
    for (int it = 0; it < 511; ++it) {
        if ((t & 15) == 1) {
            if (t > 1)
                FLUSH(t - 17)
            if (t + 15 < T_STEPS)
                LOAD_UWIN((((t + 15) >> 4) & 1), t + 15)
        }
        BODY(1)
        BODY(0)
    }
    BODY(1)   // t = 1023
#undef BODY

    // ---- epilogue: finalize y(1023), flush last window (slots 16..31) ----
    {
        if (wid == 1 && kg < 2) {
            f32x4 y_ = ypart[0][ypIdx] + ypart[1][ypIdx] + ypart[2][ypIdx] + ypart[3][ypIdx];
            *(f32x4*)&ybuf[31 * YBSTR + col * 8 + kg * 4] = y_;
        }
        __syncthreads();
        const f32x4* yp_ = (const f32x4*)&ybuf[(16 + ftoff) * YBSTR + frow * 8];
        f32x4 v0 = yp_[0], v1 = yp_[1];
        float* op = out + ((size_t)(b0 + frow) * T_STEPS + 1008 + ftoff) * NY;
        *(f32x4*)op = v0;
        *(f32x4*)(op + 4) = v1;
    }
#undef FLUSH
#undef LOAD_UWIN
}

extern "C" void kernel_launch(void* const* d_in, const int* in_sizes, int n_in,
                              void* d_out, int out_size, void* d_ws, size_t ws_size,
                              hipStream_t stream) {
    (void)in_sizes; (void)n_in; (void)d_ws; (void)ws_size; (void)out_size;
    const float* u  = (const float*)d_in[0];
    const float* z0 = (const float*)d_in[1];
    const float* W1 = (const float*)d_in[2];
    const float* b1 = (const float*)d_in[3];
    const float* W2 = (const float*)d_in[4];
    const float* b2 = (const float*)d_in[5];
    const float* W3 = (const float*)d_in[6];
    const float* b3 = (const float*)d_in[7];
    float* out = (float*)d_out;

    dim3 grid(8192 / 16);   // 512 blocks x 4 waves; 16 batch rows/block
    dim3 block(256);
    cstr_scan_kernel<<<grid, block, 0, stream>>>(u, z0, W1, b1, W2, b2, W3, b3, out);
}